// Round 9
// baseline (42.157 us; speedup 1.0000x reference)
//
#include <hip/hip_runtime.h>

// FFD cubic B-spline flow generation, separable (x -> y -> z), barrier-free.
// mesh: [4][3][23][27][23] f32, out: [4][3][160][192][160] f32, spacing 8 all
// axes -> d=(i&7)/8 (8 weight rows shared by all axes), pivot = i>>3.
//
// R9: no LDS weight table — every lane's weight-row index is a lane-constant,
// so weights are computed in registers (cubic polynomial, ~12 VALU/row).
// Mesh loads hoisted to the very top (before any LDS op / compiler barrier)
// so L2 latency hides under weight math. Wave-private LDS regions; only sync
// is s_waitcnt lgkmcnt(0) within the wave.
// (R6 lesson: non-temporal stores regress badly — plain stores only.)

#define SPX 160
#define SPY 192
#define SPZ 160
#define CPX 23
#define CPY 27
#define CPZ 23
#define MXS (CPY * CPZ)   // 621, mesh x-plane stride

// wave-local LDS sync: all prior DS ops retired -> data visible to this wave
#define WAVE_LDS_SYNC() asm volatile("s_waitcnt lgkmcnt(0)" ::: "memory")

__device__ __forceinline__ float4 bspline_w(float d) {
    float d2 = d * d, d3 = d2 * d, e = 1.0f - d;
    float4 w;
    w.x = e * e * e * (1.0f / 6.0f);
    w.y = 0.5f * d3 - d2 + (2.0f / 3.0f);
    w.z = -0.5f * d3 + 0.5f * d2 + 0.5f * d + (1.0f / 6.0f);
    w.w = d3 * (1.0f / 6.0f);
    return w;
}

__global__ __launch_bounds__(256, 8) void ffd_kernel(const float* __restrict__ mesh,
                                                     float* __restrict__ out) {
    const int yb   = blockIdx.x;   // 0..23  (y block of 8)
    const int xb   = blockIdx.y;   // 0..19  (x block of 8)
    const int bc   = blockIdx.z;   // 0..11  (b*3 + c)
    const int tid  = threadIdx.x;
    const int lane = tid & 63;
    const int wid  = tid >> 6;     // 0..3, wave owns x8 = 2*wid + {0,1}

    // xh stride 26 (not 24): stage-B b128 reads land 2-way max on banks.
    __shared__ __align__(16) float tXw[4][2][26][4];   // [wave][xh][cz][b2]
    __shared__ __align__(16) float tXYw[4][2][8][24];  // [wave][xh][y8][cz]

    // ---- hoisted mesh loads: 12 scalar L2-resident loads, issued before any
    // LDS op so their latency hides under the register weight computation.
    const int b2A  = lane & 3;          // lane-constant
    const int xhA  = (lane >> 2) & 1;   // lane-constant
    const int czA0 = lane >> 3;         // cz = czA0 + 8j
    const float* mbase = mesh + (size_t)bc * (CPX * CPY * CPZ)
                              + (size_t)xb * MXS + (size_t)yb * CPZ;
    const float* mpA = mbase + b2A * CPZ + czA0;
    float mv[3][4];
    #pragma unroll
    for (int j = 0; j < 3; ++j) {
        if (j < 2 || lane < 56) {       // 184 values/wave
            const float* mp = mpA + 8 * j;
            mv[j][0] = mp[0];
            mv[j][1] = mp[MXS];
            mv[j][2] = mp[2 * MXS];
            mv[j][3] = mp[3 * MXS];
        }
    }

    // ---- per-lane register weights (overlap the loads)
    const float4 wxA = bspline_w((float)(2 * wid + xhA) * 0.125f);
    const int    y8B = lane & 7;        // lane-constant across stage-B iters
    const float4 wyB = bspline_w((float)y8B * 0.125f);

    // ---- stage A: x-contraction -> tXw
    #pragma unroll
    for (int j = 0; j < 3; ++j) {
        if (j < 2 || lane < 56) {
            float acc = wxA.x * mv[j][0] + wxA.y * mv[j][1]
                      + wxA.z * mv[j][2] + wxA.w * mv[j][3];
            tXw[wid][xhA][czA0 + 8 * j][b2A] = acc;
        }
    }
    WAVE_LDS_SYNC();

    // ---- stage B: y-contraction -> tXYw
    const int xhB  = (lane >> 3) & 1;   // lane-constant
    const int czB0 = lane >> 4;         // cz = czB0 + 4j
    #pragma unroll
    for (int j = 0; j < 6; ++j) {
        if (j < 5 || lane < 48) {       // 368 values/wave
            int cz = czB0 + 4 * j;
            const float4 t4 = *(const float4*)&tXw[wid][xhB][cz][0];  // b128 broadcast
            tXYw[wid][xhB][y8B][cz] = wyB.x * t4.x + wyB.y * t4.y
                                    + wyB.z * t4.z + wyB.w * t4.w;
        }
    }
    WAVE_LDS_SYNC();

    // ---- stage C: expand z + store. lane = (y8, zt); full 128B line per inst.
    // out z = 32k + 4*zt + e' -> q = 4k + (zt>>1), W rows 4*(zt&1)..+3.
    const int zt = lane & 7;
    const int y8 = lane >> 3;
    const int h  = zt & 1;
    const int qo = zt >> 1;
    const float4 Wr0 = bspline_w((float)(4 * h + 0) * 0.125f);
    const float4 Wr1 = bspline_w((float)(4 * h + 1) * 0.125f);
    const float4 Wr2 = bspline_w((float)(4 * h + 2) * 0.125f);
    const float4 Wr3 = bspline_w((float)(4 * h + 3) * 0.125f);

    float* oblk = out + ((size_t)bc * SPX * SPY
                       + (size_t)(xb * 8) * SPY
                       + (size_t)(yb * 8)) * SPZ;
    #pragma unroll
    for (int xh = 0; xh < 2; ++xh) {
        int x8 = 2 * wid + xh;
        const float* tcol = &tXYw[wid][xh][y8][0];
        float* orow = oblk + ((size_t)x8 * SPY + (size_t)y8) * SPZ;
        #pragma unroll
        for (int k = 0; k < 5; ++k) {
            int qa = 4 * k + qo;
            float m0 = tcol[qa];
            float m1 = tcol[qa + 1];
            float m2 = tcol[qa + 2];
            float m3 = tcol[qa + 3];
            float4 o;
            o.x = Wr0.x * m0 + Wr0.y * m1 + Wr0.z * m2 + Wr0.w * m3;
            o.y = Wr1.x * m0 + Wr1.y * m1 + Wr1.z * m2 + Wr1.w * m3;
            o.z = Wr2.x * m0 + Wr2.y * m1 + Wr2.z * m2 + Wr2.w * m3;
            o.w = Wr3.x * m0 + Wr3.y * m1 + Wr3.z * m2 + Wr3.w * m3;
            *(float4*)&orow[32 * k + 4 * zt] = o;
        }
    }
}

extern "C" void kernel_launch(void* const* d_in, const int* in_sizes, int n_in,
                              void* d_out, int out_size, void* d_ws, size_t ws_size,
                              hipStream_t stream) {
    const float* mesh = (const float*)d_in[0];
    float* out = (float*)d_out;
    dim3 grid(SPY / 8, SPX / 8, 4 * 3);   // (24, 20, 12) = 5760 blocks
    ffd_kernel<<<grid, 256, 0, stream>>>(mesh, out);
}